// Round 19
// baseline (89.445 us; speedup 1.0000x reference)
//
#include <hip/hip_runtime.h>
#include <hip/hip_bf16.h>
#include <math.h>

#define HD 256
#define BB 64
#define DD 2048
#define QBLK 128        // rows per k_scores4 block
#define NSTS 4          // 32-row sub-tiles per block

typedef __attribute__((ext_vector_type(8))) short  short8;
typedef __attribute__((ext_vector_type(4))) float  float4v;
typedef __attribute__((ext_vector_type(4))) unsigned uint4v;
typedef __attribute__((ext_vector_type(4))) unsigned short ushort4v;

__device__ inline unsigned short f2bf(float f) {
    unsigned u = __builtin_bit_cast(unsigned, f);
    u += 0x7FFFu + ((u >> 16) & 1u);   // RNE
    return (unsigned short)(u >> 16);
}

__device__ inline short8 cvt8(float4v lo, float4v hi) {
    uint4v u;
    asm("v_cvt_pk_bf16_f32 %0, %1, %2" : "=v"(u[0]) : "v"(lo[0]), "v"(lo[1]));
    asm("v_cvt_pk_bf16_f32 %0, %1, %2" : "=v"(u[1]) : "v"(lo[2]), "v"(lo[3]));
    asm("v_cvt_pk_bf16_f32 %0, %1, %2" : "=v"(u[2]) : "v"(hi[0]), "v"(hi[1]));
    asm("v_cvt_pk_bf16_f32 %0, %1, %2" : "=v"(u[3]) : "v"(hi[2]), "v"(hi[3]));
    return __builtin_bit_cast(short8, u);
}

__device__ inline float fast_exp2(float x) {
    float r;
    asm("v_exp_f32 %0, %1" : "=v"(r) : "v"(x));
    return r;
}
__device__ inline float fast_tanh(float x) {
    float y = x * 2.8853900817779268f;          // 2x * log2(e)
    y = fminf(fmaxf(y, -30.f), 30.f);
    float t = fast_exp2(y);
    float r;
    asm("v_rcp_f32 %0, %1" : "=v"(r) : "v"(t + 1.f));
    return (t - 1.f) * r;
}

// LDS-only barrier: orders LDS traffic without draining vmcnt -> prefetch
// global loads (in staging regs) stay in flight across it.
#define SYNC_LDS() do { asm volatile("s_waitcnt lgkmcnt(0)" ::: "memory"); \
                        __builtin_amdgcn_s_barrier(); \
                        asm volatile("" ::: "memory"); } while (0)

// ---------------- kernel 0 (fused prep): W1 f32->bf16  AND  g23 ----------------
__global__ __launch_bounds__(256) void k_prep(const float* __restrict__ W1,
                                              unsigned short* __restrict__ w1b,
                                              const float* __restrict__ ctx,
                                              const float* __restrict__ hid,
                                              const float* __restrict__ W2,
                                              const float* __restrict__ b2,
                                              const float* __restrict__ W3,
                                              float* __restrict__ g23) {
    if (blockIdx.x < 64) {
        int i = blockIdx.x * 256 + threadIdx.x;
        float4v v = ((const float4v*)W1)[i];
        ushort4v o;
        o[0] = f2bf(v[0]); o[1] = f2bf(v[1]); o[2] = f2bf(v[2]); o[3] = f2bf(v[3]);
        ((ushort4v*)w1b)[i] = o;
    } else {
        int b = blockIdx.x - 64, t = threadIdx.x;
        __shared__ float c[HD], hh[HD];
        c[t]  = ctx[b * HD + t];
        hh[t] = hid[b * HD + t];
        __syncthreads();
        const float4v* w2 = (const float4v*)(W2 + (size_t)t * HD);
        const float4v* w3 = (const float4v*)(W3 + (size_t)t * HD);
        float acc = b2[t];
        #pragma unroll 8
        for (int k = 0; k < 64; ++k) {
            float4v a = w2[k], d = w3[k];
            int k4 = k * 4;
            acc += c[k4] * a[0] + c[k4 + 1] * a[1] + c[k4 + 2] * a[2] + c[k4 + 3] * a[3];
            acc += hh[k4] * d[0] + hh[k4 + 1] * d[1] + hh[k4 + 2] * d[2] + hh[k4 + 3] * d[3];
        }
        g23[b * HD + t] = acc;
    }
}

// ---------------- kernel 1: h-half partial scores, 4-wave blocks ---------------
// grid (16, 2, 64) = 2048 blocks (~4 independent blocks/CU: the TLP axis).
// Block = 256 thr / 4 waves; wave owns 32 h of its h-half (bfr = 64 VGPR).
// Per 32-row sub-tile: B1 -> cvt+conflict-free ds_write -> issue next loads ->
// B2 -> passA (MFMA + tanh.W4 + 2 shfl) -> B3 -> 4-way sum -> f32 partial to ws.
__global__ __launch_bounds__(256) void k_scores4(const float* __restrict__ q,
                                                 const unsigned short* __restrict__ w1b,
                                                 const float* __restrict__ g23,
                                                 const float* __restrict__ W4,
                                                 float* __restrict__ spart) {
    __shared__ __attribute__((aligned(16))) unsigned short tile[32 * HD];  // 16 KB
    __shared__ float sp[4][32];

    const int t = threadIdx.x;
    const int chunk = blockIdx.x, hh = blockIdx.y, b = blockIdx.z;
    const int lane = t & 63, wave = t >> 6;
    const int l15 = lane & 15, lk = lane >> 4;
    const int hb = hh * 128 + wave * 32;

    const float* qc = q + ((size_t)b * DD + chunk * QBLK) * HD;

    // staging geometry: thread t covers rows (t>>5)+p*8 (p=0..3), 16B-chunk t&31
    const int srow = t >> 5, schk = t & 31;
    const int swz = (srow & 7) << 4;        // rows differ by 8 -> same swizzle

    // prologue: issue sub-tile 0 loads (8 x dwordx4 = 32 VGPR)
    float4v s0, s1, s2, s3, s4, s5, s6, s7;
    {
        const float* p0 = qc + (size_t)srow * HD + schk * 8;
        s0 = *(const float4v*)(p0);               s1 = *(const float4v*)(p0 + 4);
        s2 = *(const float4v*)(p0 + 8 * HD);      s3 = *(const float4v*)(p0 + 8 * HD + 4);
        s4 = *(const float4v*)(p0 + 16 * HD);     s5 = *(const float4v*)(p0 + 16 * HD + 4);
        s6 = *(const float4v*)(p0 + 24 * HD);     s7 = *(const float4v*)(p0 + 24 * HD + 4);
    }

    // W1 slice -> 64 VGPR (L2-hot after k_prep)
    short8 bfr[8][2];
    #pragma unroll
    for (int kb = 0; kb < 8; ++kb)
        #pragma unroll
        for (int nf = 0; nf < 2; ++nf)
            bfr[kb][nf] = *(const short8*)&w1b[(size_t)(hb + nf * 16 + l15) * HD + kb * 32 + lk * 8];

    // per-lane g23/W4 for C rows h = hb + nf*16 + lk*4 + r
    float gv[2][4], wv[2][4];
    #pragma unroll
    for (int nf = 0; nf < 2; ++nf)
        #pragma unroll
        for (int r = 0; r < 4; ++r) {
            int h = hb + nf * 16 + lk * 4 + r;
            gv[nf][r] = g23[b * HD + h];
            wv[nf][r] = W4[h];
        }

    #pragma unroll 1
    for (int ts = 0; ts < NSTS; ++ts) {
        SYNC_LDS();   // B1: all waves done reading tile (prev passA)

        // stage: cvt once -> 4 conflict-free ds_write_b128 (wave = contiguous 1KB)
        {
            short8 p0 = cvt8(s0, s1);
            short8 p1 = cvt8(s2, s3);
            short8 p2 = cvt8(s4, s5);
            short8 p3 = cvt8(s6, s7);
            int base = srow * 512 + ((schk * 16) ^ swz);
            *(short8*)((char*)tile + base)            = p0;
            *(short8*)((char*)tile + base + 8 * 512)  = p1;
            *(short8*)((char*)tile + base + 16 * 512) = p2;
            *(short8*)((char*)tile + base + 24 * 512) = p3;
        }
        // issue next sub-tile's loads: fly across B2 + passA + B3 + B1
        if (ts + 1 < NSTS) {
            const float* pn = qc + (size_t)((ts + 1) * 32 + srow) * HD + schk * 8;
            s0 = *(const float4v*)(pn);               s1 = *(const float4v*)(pn + 4);
            s2 = *(const float4v*)(pn + 8 * HD);      s3 = *(const float4v*)(pn + 8 * HD + 4);
            s4 = *(const float4v*)(pn + 16 * HD);     s5 = *(const float4v*)(pn + 16 * HD + 4);
            s6 = *(const float4v*)(pn + 24 * HD);     s7 = *(const float4v*)(pn + 24 * HD + 4);
        }
        SYNC_LDS();   // B2: tile staged by all waves

        // passA: C[32 h][32 d] per wave; bf16 frags read directly
        #pragma unroll
        for (int mf = 0; mf < 2; ++mf) {
            float4v acc0 = {0.f, 0.f, 0.f, 0.f}, acc1 = {0.f, 0.f, 0.f, 0.f};
            const int d = mf * 16 + l15;
            const int dsw = (d & 7) << 4;
            #pragma unroll
            for (int kb = 0; kb < 8; ++kb) {
                int byte = d * 512 + ((kb * 64 + lk * 16) ^ dsw);
                short8 bq = *(const short8*)((const char*)tile + byte);
                acc0 = __builtin_amdgcn_mfma_f32_16x16x32_bf16(bfr[kb][0], bq, acc0, 0, 0, 0);
                acc1 = __builtin_amdgcn_mfma_f32_16x16x32_bf16(bfr[kb][1], bq, acc1, 0, 0, 0);
            }
            float s = 0.f;
            #pragma unroll
            for (int r = 0; r < 4; ++r) s += fast_tanh(acc0[r] + gv[0][r]) * wv[0][r];
            #pragma unroll
            for (int r = 0; r < 4; ++r) s += fast_tanh(acc1[r] + gv[1][r]) * wv[1][r];
            s += __shfl_xor(s, 16, 64);
            s += __shfl_xor(s, 32, 64);
            if (lk == 0) sp[wave][mf * 16 + l15] = s;
        }
        SYNC_LDS();   // B3: sp published

        // 4-way h-group sum -> f32 partial score for this h-half
        if (t < 32) {
            float s = sp[0][t] + sp[1][t] + sp[2][t] + sp[3][t];
            spart[((size_t)(b * DD + chunk * QBLK + ts * 32 + t)) * 2 + hh] = s;
        }
    }
}

// ---------------- kernel 2: combine h-halves, bounded exp, 1/L -----------------
__global__ __launch_bounds__(256) void k_stats(const float* __restrict__ spart,
                                               float* __restrict__ wexp,
                                               float* __restrict__ stats) {
    int b = blockIdx.x, t = threadIdx.x;
    __shared__ float red[256];
    float lsum = 0.f;
    #pragma unroll
    for (int i = 0; i < 8; ++i) {
        int d = t + i * 256;
        const float* p = &spart[((size_t)(b * DD + d)) * 2];
        float s = p[0] + p[1];           // |s| <= sum|W4| ~ 8: plain exp fp32-safe
        float w = fast_exp2(s * 1.4426950408889634f);
        wexp[b * DD + d] = w;
        lsum += w;
    }
    red[t] = lsum; __syncthreads();
    for (int s = 128; s > 0; s >>= 1) {
        if (t < s) red[t] += red[t + s];
        __syncthreads();
    }
    if (t == 0) stats[b] = 1.f / red[0];
}

// ---------------- kernel 3: partial weighted sums (L3-hot second q pass) -------
__global__ __launch_bounds__(256) void k_pout(const float* __restrict__ q,
                                              const float* __restrict__ wexp,
                                              const float* __restrict__ stats,
                                              float* __restrict__ part) {
    const int b = blockIdx.y, ch = blockIdx.x, t = threadIdx.x;
    __shared__ float wl[256];
    __shared__ float4v red[256];
    const float inv = stats[b];
    const int d0 = ch * 256;
    wl[t] = wexp[b * DD + d0 + t] * inv;
    __syncthreads();
    const int rg = t >> 6, cg = t & 63;       // row-group, col-float4
    const float4v* qb = (const float4v*)(q + ((size_t)(b * DD + d0 + rg)) * HD) + cg;
    float4v a0 = {0,0,0,0}, a1 = {0,0,0,0};
    #pragma unroll 8
    for (int i = 0; i < 64; i += 2) {
        a0 += qb[(size_t)i * 256]       * wl[rg + i * 4];
        a1 += qb[(size_t)(i + 1) * 256] * wl[rg + (i + 1) * 4];
    }
    red[t] = a0 + a1;
    __syncthreads();
    if (t < 64) {
        float4v s = red[t] + red[t + 64] + red[t + 128] + red[t + 192];
        ((float4v*)part)[((size_t)(b * 8 + ch)) * 64 + t] = s;
    }
}

// ---------------- kernel 4: reduce partials ----------------
__global__ __launch_bounds__(64) void k_rout(const float* __restrict__ part,
                                             float* __restrict__ out) {
    int b = blockIdx.x, t = threadIdx.x;
    float4v s = {0,0,0,0};
    #pragma unroll
    for (int c = 0; c < 8; ++c) s += ((const float4v*)part)[((size_t)(b * 8 + c)) * 64 + t];
    ((float4v*)out)[b * 64 + t] = s;
}

extern "C" void kernel_launch(void* const* d_in, const int* in_sizes, int n_in,
                              void* d_out, int out_size, void* d_ws, size_t ws_size,
                              hipStream_t stream) {
    (void)in_sizes; (void)n_in; (void)out_size; (void)ws_size;
    const float* ctx = (const float*)d_in[0];
    const float* q   = (const float*)d_in[1];
    const float* hid = (const float*)d_in[2];
    const float* W1  = (const float*)d_in[3];
    const float* W2  = (const float*)d_in[4];
    const float* b2  = (const float*)d_in[5];
    const float* W3  = (const float*)d_in[6];
    const float* W4  = (const float*)d_in[7];
    // d_in[8] = b4: cancels exactly in exp-sum ratio (softmax shift-invariance)
    float* out = (float*)d_out;

    char* ws = (char*)d_ws;
    unsigned short* w1b = (unsigned short*)(ws);            // 131072 B
    float* g23   = (float*)(ws + 131072);                   //  65536 B
    float* wexp  = (float*)(ws + 196608);                   // 524288 B
    float* stats = (float*)(ws + 720896);                   //   1024 B
    float* spart = (float*)(ws + 721920);                   // 1048576 B (b,d,2)
    float* part  = (float*)(ws + 721920);                   // 524288 B — ALIASES
    // spart: safe, k_pout/k_rout never read spart after k_stats consumes it.

    k_prep   <<<dim3(128), dim3(256), 0, stream>>>(W1, w1b, ctx, hid, W2, b2, W3, g23);
    k_scores4<<<dim3(DD / QBLK, 2, BB), dim3(256), 0, stream>>>(q, w1b, g23, W4, spart);
    k_stats  <<<dim3(BB), dim3(256), 0, stream>>>(spart, wexp, stats);
    k_pout   <<<dim3(8, BB), dim3(256), 0, stream>>>(q, wexp, stats, part);
    k_rout   <<<dim3(BB), dim3(64), 0, stream>>>(part, out);
}

// Round 20
// 63.274 us; speedup vs baseline: 1.4136x; 1.4136x over previous
//
#include <hip/hip_runtime.h>
#include <hip/hip_bf16.h>
#include <math.h>

#define HD 256
#define BB 64
#define DD 2048
#define NCHK 4          // 512-row chunks per batch (1 block per CU)
#define NST 8           // 64-row sub-tiles per chunk

typedef __attribute__((ext_vector_type(8))) short  short8;
typedef __attribute__((ext_vector_type(4))) float  float4v;
typedef __attribute__((ext_vector_type(4))) unsigned uint4v;
typedef __attribute__((ext_vector_type(4))) unsigned short ushort4v;

__device__ inline unsigned short f2bf(float f) {
    unsigned u = __builtin_bit_cast(unsigned, f);
    u += 0x7FFFu + ((u >> 16) & 1u);   // RNE
    return (unsigned short)(u >> 16);
}
__device__ inline float bf2f(unsigned short u) {
    return __builtin_bit_cast(float, (unsigned)u << 16);
}

__device__ inline short8 cvt8(float4v lo, float4v hi) {
    uint4v u;
    asm("v_cvt_pk_bf16_f32 %0, %1, %2" : "=v"(u[0]) : "v"(lo[0]), "v"(lo[1]));
    asm("v_cvt_pk_bf16_f32 %0, %1, %2" : "=v"(u[1]) : "v"(lo[2]), "v"(lo[3]));
    asm("v_cvt_pk_bf16_f32 %0, %1, %2" : "=v"(u[2]) : "v"(hi[0]), "v"(hi[1]));
    asm("v_cvt_pk_bf16_f32 %0, %1, %2" : "=v"(u[3]) : "v"(hi[2]), "v"(hi[3]));
    return __builtin_bit_cast(short8, u);
}

__device__ inline float fast_exp2(float x) {
    float r;
    asm("v_exp_f32 %0, %1" : "=v"(r) : "v"(x));
    return r;
}
__device__ inline float fast_tanh(float x) {
    float y = x * 2.8853900817779268f;          // 2x * log2(e)
    y = fminf(fmaxf(y, -30.f), 30.f);
    float t = fast_exp2(y);
    float r;
    asm("v_rcp_f32 %0, %1" : "=v"(r) : "v"(t + 1.f));
    return (t - 1.f) * r;
}

// LDS-only barrier: orders LDS traffic without draining vmcnt -> prefetch
// global loads (in staging regs) stay in flight across it.
#define SYNC_LDS() do { asm volatile("s_waitcnt lgkmcnt(0)" ::: "memory"); \
                        __builtin_amdgcn_s_barrier(); \
                        asm volatile("" ::: "memory"); } while (0)

// ---------------- kernel 0 (fused prep): W1 f32->bf16  AND  g23 ----------------
__global__ __launch_bounds__(256) void k_prep(const float* __restrict__ W1,
                                              unsigned short* __restrict__ w1b,
                                              const float* __restrict__ ctx,
                                              const float* __restrict__ hid,
                                              const float* __restrict__ W2,
                                              const float* __restrict__ b2,
                                              const float* __restrict__ W3,
                                              float* __restrict__ g23) {
    if (blockIdx.x < 64) {
        int i = blockIdx.x * 256 + threadIdx.x;
        float4v v = ((const float4v*)W1)[i];
        ushort4v o;
        o[0] = f2bf(v[0]); o[1] = f2bf(v[1]); o[2] = f2bf(v[2]); o[3] = f2bf(v[3]);
        ((ushort4v*)w1b)[i] = o;
    } else {
        int b = blockIdx.x - 64, t = threadIdx.x;
        __shared__ float c[HD], hh[HD];
        c[t]  = ctx[b * HD + t];
        hh[t] = hid[b * HD + t];
        __syncthreads();
        const float4v* w2 = (const float4v*)(W2 + (size_t)t * HD);
        const float4v* w3 = (const float4v*)(W3 + (size_t)t * HD);
        float acc = b2[t];
        #pragma unroll 8
        for (int k = 0; k < 64; ++k) {
            float4v a = w2[k], d = w3[k];
            int k4 = k * 4;
            acc += c[k4] * a[0] + c[k4 + 1] * a[1] + c[k4 + 2] * a[2] + c[k4 + 3] * a[3];
            acc += hh[k4] * d[0] + hh[k4 + 1] * d[1] + hh[k4 + 2] * d[2] + hh[k4 + 3] * d[3];
        }
        g23[b * HD + t] = acc;
    }
}

// ---------------- kernel 1: fused pipeline, one block per CU -------------------
// grid (4, 64) = 256 blocks = EXACTLY 1/CU: one prologue/epilogue per CU
// (r18's 512 blocks paid it twice). Otherwise r18 verbatim: 512 thr, 8 waves;
// wave owns 32 h (bfr = 64 VGPR); LDS = 32KB bf16 tile + 1KB bf16 sp = 33792 B;
// conflict-free staging writes; reg-prefetch one sub-tile ahead; 3 LDS-only
// barriers; bounded exp (|s| <= sum|W4| ~ 8 => no max chains, no rescale).
__global__ __launch_bounds__(512) void k_fused(const float* __restrict__ q,
                                               const unsigned short* __restrict__ w1b,
                                               const float* __restrict__ g23,
                                               const float* __restrict__ W4,
                                               float* __restrict__ pl,
                                               float* __restrict__ pO) {
    __shared__ __attribute__((aligned(16))) unsigned short tile[64 * HD];  // 32 KB
    __shared__ __attribute__((aligned(16))) unsigned short spb[64][8];     // 1 KB

    const int t = threadIdx.x;
    const int chunk = blockIdx.x, b = blockIdx.y;
    const int lane = t & 63, wave = t >> 6;
    const int l15 = lane & 15, lk = lane >> 4;
    const int hb = wave * 32;
    const int cg = lane & 7, ro = lane >> 3;   // PV: col-quad (4 cols), row-oct

    const float* qc = q + ((size_t)b * DD + chunk * 512) * HD;

    // staging geometry: thread t covers rows (t>>5)+p*16, 16B-chunk t&31
    const int srow = t >> 5, schk = t & 31;
    const int swz = (srow & 7) << 4;            // row-constant across p

    // prologue: issue sub-tile 0 loads (8 x dwordx4 = 32 VGPR)
    float4v s0, s1, s2, s3, s4, s5, s6, s7;
    {
        const float* p0 = qc + (size_t)srow * HD + schk * 8;
        s0 = *(const float4v*)(p0);                s1 = *(const float4v*)(p0 + 4);
        s2 = *(const float4v*)(p0 + 16 * HD);      s3 = *(const float4v*)(p0 + 16 * HD + 4);
        s4 = *(const float4v*)(p0 + 32 * HD);      s5 = *(const float4v*)(p0 + 32 * HD + 4);
        s6 = *(const float4v*)(p0 + 48 * HD);      s7 = *(const float4v*)(p0 + 48 * HD + 4);
    }

    // W1 slice -> 64 VGPR (L2-hot after k_prep)
    short8 bfr[8][2];
    #pragma unroll
    for (int kb = 0; kb < 8; ++kb)
        #pragma unroll
        for (int nf = 0; nf < 2; ++nf)
            bfr[kb][nf] = *(const short8*)&w1b[(size_t)(hb + nf * 16 + l15) * HD + kb * 32 + lk * 8];

    // per-lane g23/W4 in registers (16 VGPR)
    float gv[2][4], wv[2][4];
    #pragma unroll
    for (int nf = 0; nf < 2; ++nf)
        #pragma unroll
        for (int r = 0; r < 4; ++r) {
            int h = hb + nf * 16 + lk * 4 + r;
            gv[nf][r] = g23[b * HD + h];
            wv[nf][r] = W4[h];
        }

    float l = 0.f;
    float4v O = {0.f, 0.f, 0.f, 0.f};

    #pragma unroll 1
    for (int ts = 0; ts < NST; ++ts) {
        SYNC_LDS();   // B1: all waves done reading tile (prev passA/passB)

        // stage tile ts: cvt once -> 4 conflict-free contiguous ds_write_b128
        {
            short8 p0 = cvt8(s0, s1);
            short8 p1 = cvt8(s2, s3);
            short8 p2 = cvt8(s4, s5);
            short8 p3 = cvt8(s6, s7);
            int base = srow * 512 + ((schk * 16) ^ swz);
            *(short8*)((char*)tile + base)              = p0;
            *(short8*)((char*)tile + base + 16 * 512)   = p1;
            *(short8*)((char*)tile + base + 32 * 512)   = p2;
            *(short8*)((char*)tile + base + 48 * 512)   = p3;
        }
        // issue next sub-tile's loads: fly across B2 + passA + B3 + passB + B1
        if (ts + 1 < NST) {
            const float* pn = qc + (size_t)((ts + 1) * 64 + srow) * HD + schk * 8;
            s0 = *(const float4v*)(pn);                s1 = *(const float4v*)(pn + 4);
            s2 = *(const float4v*)(pn + 16 * HD);      s3 = *(const float4v*)(pn + 16 * HD + 4);
            s4 = *(const float4v*)(pn + 32 * HD);      s5 = *(const float4v*)(pn + 32 * HD + 4);
            s6 = *(const float4v*)(pn + 48 * HD);      s7 = *(const float4v*)(pn + 48 * HD + 4);
        }
        SYNC_LDS();   // B2: tile ts fully staged by all waves

        // ---- passA: partial scores, bf16 frags read directly (no cvt) ----
        #pragma unroll
        for (int mf = 0; mf < 4; ++mf) {
            float4v acc0 = {0.f, 0.f, 0.f, 0.f}, acc1 = {0.f, 0.f, 0.f, 0.f};
            const int d = mf * 16 + l15;
            const int dsw = (d & 7) << 4;
            #pragma unroll
            for (int kb = 0; kb < 8; ++kb) {
                int byte = d * 512 + ((kb * 64 + lk * 16) ^ dsw);
                short8 bq = *(const short8*)((const char*)tile + byte);
                acc0 = __builtin_amdgcn_mfma_f32_16x16x32_bf16(bfr[kb][0], bq, acc0, 0, 0, 0);
                acc1 = __builtin_amdgcn_mfma_f32_16x16x32_bf16(bfr[kb][1], bq, acc1, 0, 0, 0);
            }
            float s = 0.f;
            #pragma unroll
            for (int r = 0; r < 4; ++r) s += fast_tanh(acc0[r] + gv[0][r]) * wv[0][r];
            #pragma unroll
            for (int r = 0; r < 4; ++r) s += fast_tanh(acc1[r] + gv[1][r]) * wv[1][r];
            s += __shfl_xor(s, 16, 64);
            s += __shfl_xor(s, 32, 64);
            if (lk == 0) spb[mf * 16 + l15][wave] = f2bf(s);
        }
        SYNC_LDS();   // B3: spb published

        // ---- passB: bounded exp (no max chains, no rescale) + PV ----
        float sc;
        {
            ushort4v a = *(const ushort4v*)&spb[lane][0];
            ushort4v c = *(const ushort4v*)&spb[lane][4];
            sc = bf2f(a[0]) + bf2f(a[1]) + bf2f(a[2]) + bf2f(a[3])
               + bf2f(c[0]) + bf2f(c[1]) + bf2f(c[2]) + bf2f(c[3]);
        }
        float w = fast_exp2(sc * 1.4426950408889634f);
        l += w;                          // lane's row = lane
        // PV: wave cols [wave*32, +32); lane owns 4 cols (cg*4), rows ro*8+i
        const int cb = wave * 64 + cg * 8;   // byte offset of 4 bf16 cols
        #pragma unroll
        for (int i = 0; i < 8; ++i) {
            int d = ro * 8 + i;
            float wd = __shfl(w, d, 64);
            int byte = d * 512 + (cb ^ ((d & 7) << 4));
            ushort4v v = *(const ushort4v*)((const char*)tile + byte);
            O[0] += wd * bf2f(v[0]);
            O[1] += wd * bf2f(v[1]);
            O[2] += wd * bf2f(v[2]);
            O[3] += wd * bf2f(v[3]);
        }
    }

    // reduce O over the 8 row-octs (lanes sharing cg)
    #pragma unroll
    for (int j = 0; j < 4; ++j) {
        O[j] += __shfl_xor(O[j], 8, 64);
        O[j] += __shfl_xor(O[j], 16, 64);
        O[j] += __shfl_xor(O[j], 32, 64);
    }
    if (ro == 0)
        *(float4v*)&pO[((size_t)(b * NCHK + chunk)) * HD + wave * 32 + cg * 4] = O;

    // reduce l over 64 lanes (identical across waves); one write
    l += __shfl_xor(l, 1, 64);
    l += __shfl_xor(l, 2, 64);
    l += __shfl_xor(l, 4, 64);
    l += __shfl_xor(l, 8, 64);
    l += __shfl_xor(l, 16, 64);
    l += __shfl_xor(l, 32, 64);
    if (t == 0) pl[b * NCHK + chunk] = l;
}

// ---------------- kernel 2: combine 4 chunk-partials per batch -----------------
__global__ __launch_bounds__(256) void k_comb(const float* __restrict__ pl,
                                              const float* __restrict__ pO,
                                              float* __restrict__ out) {
    int b = blockIdx.x, t = threadIdx.x;
    float L = 0.f;
    #pragma unroll
    for (int c = 0; c < NCHK; ++c) L += pl[b * NCHK + c];
    float s = 0.f;
    #pragma unroll
    for (int c = 0; c < NCHK; ++c) s += pO[((size_t)(b * NCHK + c)) * HD + t];
    out[b * HD + t] = s / L;
}

extern "C" void kernel_launch(void* const* d_in, const int* in_sizes, int n_in,
                              void* d_out, int out_size, void* d_ws, size_t ws_size,
                              hipStream_t stream) {
    (void)in_sizes; (void)n_in; (void)out_size; (void)ws_size;
    const float* ctx = (const float*)d_in[0];
    const float* q   = (const float*)d_in[1];
    const float* hid = (const float*)d_in[2];
    const float* W1  = (const float*)d_in[3];
    const float* W2  = (const float*)d_in[4];
    const float* b2  = (const float*)d_in[5];
    const float* W3  = (const float*)d_in[6];
    const float* W4  = (const float*)d_in[7];
    // d_in[8] = b4: cancels exactly in exp-sum ratio (softmax shift-invariance)
    float* out = (float*)d_out;

    char* ws = (char*)d_ws;
    unsigned short* w1b = (unsigned short*)(ws);            // 131072 B
    float* g23 = (float*)(ws + 131072);                     //  65536 B
    float* pl  = (float*)(ws + 196608);                     //   1024 B
    float* pO  = (float*)(ws + 197632);                     // 262144 B

    k_prep <<<dim3(128), dim3(256), 0, stream>>>(W1, w1b, ctx, hid, W2, b2, W3, g23);
    k_fused<<<dim3(NCHK, BB), dim3(512), 0, stream>>>(q, w1b, g23, W4, pl, pO);
    k_comb <<<dim3(BB), dim3(256), 0, stream>>>(pl, pO, out);
}